// Round 8
// baseline (479.481 us; speedup 1.0000x reference)
//
#include <hip/hip_runtime.h>
#include <stdint.h>

#define EPS 1e-5f

typedef short bf16x8 __attribute__((ext_vector_type(8)));
typedef float f32x4 __attribute__((ext_vector_type(4)));

constexpr int M = 1024, N = 4096, K = 4096;
constexpr int BM = 64, BN = 128, BK = 64;
constexpr int NTK = K / BK;                      // 64 K-steps
constexpr int GEMM_GRID = (M / BM) * (N / BN);   // 512 blocks
constexpr int NPROD = GEMM_GRID;                 // contributions per flag
constexpr int GRP = 8;                           // K-slabs per flag group
constexpr int NFLAGS = NTK / GRP;                // 8

// padded LDS: 64 KB total -> hard cap 2 blocks/CU -> 512 blocks all co-resident
constexpr int LDS_ELEMS = 16384;                 // shorts per buffer (24 KB used, padded to 32 KB)

// ---------- helpers ----------
__device__ __forceinline__ unsigned short f2bf(float f) {
  union { float f; uint32_t u; } v; v.f = f;
  uint32_t r = (v.u + 0x7fffu + ((v.u >> 16) & 1u)) >> 16;  // RNE
  return (unsigned short)r;
}

__device__ __forceinline__ void gload16(const void* g, void* l) {
  __builtin_amdgcn_global_load_lds(
      (const __attribute__((address_space(1))) void*)(uintptr_t)g,
      (__attribute__((address_space(3))) void*)(uintptr_t)l, 16, 0, 0);
}

__device__ __forceinline__ void cvt8(const f32x4& a0, const f32x4& a1,
                                     const f32x4& s0, const f32x4& s1,
                                     const f32x4& n0, const f32x4& n1,
                                     bf16x8& o) {
  o[0] = (short)f2bf(a0[0] + n0[0] * fmaxf(__expf(s0[0]), EPS));
  o[1] = (short)f2bf(a0[1] + n0[1] * fmaxf(__expf(s0[1]), EPS));
  o[2] = (short)f2bf(a0[2] + n0[2] * fmaxf(__expf(s0[2]), EPS));
  o[3] = (short)f2bf(a0[3] + n0[3] * fmaxf(__expf(s0[3]), EPS));
  o[4] = (short)f2bf(a1[0] + n1[0] * fmaxf(__expf(s1[0]), EPS));
  o[5] = (short)f2bf(a1[1] + n1[1] * fmaxf(__expf(s1[1]), EPS));
  o[6] = (short)f2bf(a1[2] + n1[2] * fmaxf(__expf(s1[2]), EPS));
  o[7] = (short)f2bf(a1[3] + n1[3] * fmaxf(__expf(s1[3]), EPS));
}

// ---------- init: zero flags with agent-coherent atomics ----------
__global__ void init_flags_kernel(unsigned int* flags) {
  if (threadIdx.x < NFLAGS) atomicExch(&flags[threadIdx.x], 0u);
}

// ---------- fused: producer (fp32->bf16 prep, K-slab ordered) + consumer (MFMA GEMM) ----------
// Block b preps W rows [b*8, b*8+8) and x rows [b*2, b*2+2) of each K-slab.
// Group g = slabs [g*8,(g+1)*8): flags[g] counts block contributions (NPROD when ready).
// GEMM step t consumes slab t; gated on flags[t>>3].
__global__ __launch_bounds__(256, 2) void fused_kernel(
    const float* __restrict__ x,  const float* __restrict__ wm,
    const float* __restrict__ wsp, const float* __restrict__ bm,
    const float* __restrict__ bsp, const float* __restrict__ nb,
    const float* __restrict__ nw,
    unsigned short* __restrict__ w_bf, unsigned short* __restrict__ x_bf,
    unsigned int* __restrict__ flags, float* __restrict__ out)
{
  __shared__ unsigned short lds_mem[2][LDS_ELEMS];   // 64 KB -> exactly 2 blocks/CU

  const int bid = blockIdx.x;
  const int tid = threadIdx.x;
  const int lane = tid & 63;
  const int wid = tid >> 6;

  const f32x4* wm4  = (const f32x4*)wm;
  const f32x4* wsp4 = (const f32x4*)wsp;
  const f32x4* nw4  = (const f32x4*)nw;
  const f32x4* x4   = (const f32x4*)x;
  bf16x8* wb8 = (bf16x8*)w_bf;
  bf16x8* xb8 = (bf16x8*)x_bf;

  // prep share of slab s (80 active threads)
  auto prep_share = [&](int s) {
    if (tid < 64) {
      const int row = bid * 8 + (tid >> 3);
      const int col = s * 64 + (tid & 7) * 8;
      const int i4 = (row * K + col) >> 2;
      f32x4 a0 = wm4[i4],  a1 = wm4[i4 + 1];
      f32x4 s0 = wsp4[i4], s1 = wsp4[i4 + 1];
      f32x4 n0 = nw4[i4],  n1 = nw4[i4 + 1];
      bf16x8 o; cvt8(a0, a1, s0, s1, n0, n1, o);
      wb8[(row * K + col) >> 3] = o;
    } else if (tid < 80) {
      const int u = tid - 64;
      const int row = bid * 2 + (u >> 3);
      const int col = s * 64 + (u & 7) * 8;
      const int i4 = (row * K + col) >> 2;
      f32x4 v0 = x4[i4], v1 = x4[i4 + 1];
      bf16x8 o;
      o[0] = (short)f2bf(v0[0]); o[1] = (short)f2bf(v0[1]);
      o[2] = (short)f2bf(v0[2]); o[3] = (short)f2bf(v0[3]);
      o[4] = (short)f2bf(v1[0]); o[5] = (short)f2bf(v1[1]);
      o[6] = (short)f2bf(v1[2]); o[7] = (short)f2bf(v1[3]);
      xb8[(row * K + col) >> 3] = o;
    }
  };

  // entry acquire: invalidate stale cross-replay L1/L2 lines before any w_bf/x_bf read.
  // All blocks' invs complete before any flag can reach NPROD (inv precedes own release).
  if (tid == 0)
    (void)__hip_atomic_load(flags, __ATOMIC_ACQUIRE, __HIP_MEMORY_SCOPE_AGENT);

  // ---- GEMM tile mapping (XCD swizzle, 512 % 8 == 0) ----
  const int lid = (bid % 8) * (GEMM_GRID / 8) + bid / 8;
  const int bc = lid >> 4;     // N-tile, 0..31
  const int br = lid & 15;     // M-tile, 0..15

  const int srow = wid * 8 + (lane >> 3);
  const int scol = ((lane & 7) ^ (lane >> 3)) * 8;   // pre-swizzled 16B slot
  const unsigned short* gA = x_bf + (int64_t)(br * BM + srow) * K + scol;
  const unsigned short* gB = w_bf + (int64_t)(bc * BN + srow) * K + scol;
  const int woff = wid * 8 * BK;

  auto stage = [&](int b, int t) {
    const unsigned short* ga = gA + t * BK;
    const unsigned short* gb = gB + t * BK;
    unsigned short* la = &lds_mem[b][0] + woff;
    unsigned short* lb = &lds_mem[b][BM * BK] + woff;
    gload16(ga,          la);
    gload16(ga + 32 * K, la + 32 * BK);
    gload16(gb,          lb);
    gload16(gb + 32 * K, lb + 32 * BK);
    gload16(gb + 64 * K, lb + 64 * BK);
    gload16(gb + 96 * K, lb + 96 * BK);
  };

  // ---- prologue: prep group 0, publish, wait, stage slab 0 ----
#pragma unroll
  for (int s = 0; s < GRP; ++s) prep_share(s);
  __syncthreads();                       // drains all waves' prep stores into L2
  if (tid == 0) {
    __hip_atomic_fetch_add(&flags[0], 1u, __ATOMIC_RELEASE, __HIP_MEMORY_SCOPE_AGENT);
    while (__hip_atomic_load(&flags[0], __ATOMIC_RELAXED, __HIP_MEMORY_SCOPE_AGENT) < (unsigned)NPROD)
      __builtin_amdgcn_s_sleep(1);
  }
  __syncthreads();
  stage(0, 0);

  f32x4 acc[2][4] = {};
  const int fr = lane & 15;
  const int hi = lane >> 4;
  const int rl = lane & 7;
  const int c0 = ((hi ^ rl) << 3);
  const int c1 = (((4 + hi) ^ rl) << 3);
  const int am = (wid >> 1) * 32;
  const int an = (wid & 1) * 64;

  int cur = 0;
  for (int t = 0; t < NTK; ++t) {
    if (t + GRP < NTK) prep_share(t + GRP);     // prep group g+1 during group g's steps
    __syncthreads();                            // stage(t) + prep stores drained; buf[cur^1] free
    if ((t & (GRP - 1)) == GRP - 1) {           // group boundary
      const int rg = (t + 1) >> 3;              // group just fully prepped / next needed
      if (tid == 0) {
        if (rg < NFLAGS)
          __hip_atomic_fetch_add(&flags[rg], 1u, __ATOMIC_RELEASE, __HIP_MEMORY_SCOPE_AGENT);
        if (t + 1 < NTK)
          while (__hip_atomic_load(&flags[rg], __ATOMIC_RELAXED, __HIP_MEMORY_SCOPE_AGENT) < (unsigned)NPROD)
            __builtin_amdgcn_s_sleep(1);
      }
      __syncthreads();
    }
    if (t + 1 < NTK) stage(cur ^ 1, t + 1);
    const unsigned short* lA = &lds_mem[cur][0];
    const unsigned short* lB = &lds_mem[cur][BM * BK];
#pragma unroll
    for (int kk = 0; kk < 2; ++kk) {
      const int c = kk ? c1 : c0;
      bf16x8 a0 = *(const bf16x8*)&lA[(am +  0 + fr) * BK + c];
      bf16x8 a1 = *(const bf16x8*)&lA[(am + 16 + fr) * BK + c];
      bf16x8 b0 = *(const bf16x8*)&lB[(an +  0 + fr) * BK + c];
      bf16x8 b1 = *(const bf16x8*)&lB[(an + 16 + fr) * BK + c];
      bf16x8 b2 = *(const bf16x8*)&lB[(an + 32 + fr) * BK + c];
      bf16x8 b3 = *(const bf16x8*)&lB[(an + 48 + fr) * BK + c];
      acc[0][0] = __builtin_amdgcn_mfma_f32_16x16x32_bf16(a0, b0, acc[0][0], 0, 0, 0);
      acc[0][1] = __builtin_amdgcn_mfma_f32_16x16x32_bf16(a0, b1, acc[0][1], 0, 0, 0);
      acc[0][2] = __builtin_amdgcn_mfma_f32_16x16x32_bf16(a0, b2, acc[0][2], 0, 0, 0);
      acc[0][3] = __builtin_amdgcn_mfma_f32_16x16x32_bf16(a0, b3, acc[0][3], 0, 0, 0);
      acc[1][0] = __builtin_amdgcn_mfma_f32_16x16x32_bf16(a1, b0, acc[1][0], 0, 0, 0);
      acc[1][1] = __builtin_amdgcn_mfma_f32_16x16x32_bf16(a1, b1, acc[1][1], 0, 0, 0);
      acc[1][2] = __builtin_amdgcn_mfma_f32_16x16x32_bf16(a1, b2, acc[1][2], 0, 0, 0);
      acc[1][3] = __builtin_amdgcn_mfma_f32_16x16x32_bf16(a1, b3, acc[1][3], 0, 0, 0);
    }
    cur ^= 1;
  }

  // ---- epilogue: inline bias (bm + nb*max(exp(bsp),EPS)), C/D layout col=lane&15, row=(lane>>4)*4+reg ----
  const int orow0 = br * BM + am + hi * 4;
  const int ocol0 = bc * BN + an + fr;
#pragma unroll
  for (int j = 0; j < 4; ++j) {
    const int col = ocol0 + j * 16;
    const float bv = bm[col] + nb[col] * fmaxf(__expf(bsp[col]), EPS);
#pragma unroll
    for (int i = 0; i < 2; ++i) {
      const int row = orow0 + i * 16;
#pragma unroll
      for (int r = 0; r < 4; ++r)
        out[(int64_t)(row + r) * N + col] = acc[i][j][r] + bv;
    }
  }
}

// ---------- correctness fallback if workspace too small ----------
__global__ __launch_bounds__(256) void fallback_kernel(
    const float* __restrict__ x, const float* __restrict__ wm,
    const float* __restrict__ wsp, const float* __restrict__ bm,
    const float* __restrict__ bsp, const float* __restrict__ nw,
    const float* __restrict__ nb, float* __restrict__ out)
{
  int64_t idx = (int64_t)blockIdx.x * 256 + threadIdx.x;
  if (idx >= (int64_t)M * N) return;
  int b = (int)(idx >> 12);
  int o = (int)(idx & (N - 1));
  const float* xr = x + (int64_t)b * K;
  const float* wmr = wm + (int64_t)o * K;
  const float* wsr = wsp + (int64_t)o * K;
  const float* nwr = nw + (int64_t)o * K;
  float s = 0.f;
  for (int k = 0; k < K; ++k)
    s += xr[k] * (wmr[k] + nwr[k] * fmaxf(__expf(wsr[k]), EPS));
  out[idx] = s + bm[o] + nb[o] * fmaxf(__expf(bsp[o]), EPS);
}

extern "C" void kernel_launch(void* const* d_in, const int* in_sizes, int n_in,
                              void* d_out, int out_size, void* d_ws, size_t ws_size,
                              hipStream_t stream) {
  const float* x   = (const float*)d_in[0];
  const float* wm  = (const float*)d_in[1];
  const float* wsp = (const float*)d_in[2];
  const float* bm  = (const float*)d_in[3];
  const float* bsp = (const float*)d_in[4];
  const float* nw  = (const float*)d_in[5];
  const float* nb  = (const float*)d_in[6];
  float* out = (float*)d_out;

  const size_t w_bytes = (size_t)N * K * 2;
  const size_t x_bytes = (size_t)M * K * 2;
  const size_t f_bytes = 64 * sizeof(unsigned int);
  if (ws_size < w_bytes + x_bytes + f_bytes) {
    fallback_kernel<<<(int)(((int64_t)M * N + 255) / 256), 256, 0, stream>>>(
        x, wm, wsp, bm, bsp, nw, nb, out);
    return;
  }

  char* ws = (char*)d_ws;
  unsigned short* w_bf = (unsigned short*)ws;
  unsigned short* x_bf = (unsigned short*)(ws + w_bytes);
  unsigned int* flags = (unsigned int*)(ws + w_bytes + x_bytes);

  init_flags_kernel<<<1, 64, 0, stream>>>(flags);
  fused_kernel<<<GEMM_GRID, 256, 0, stream>>>(x, wm, wsp, bm, bsp, nb, nw,
                                              w_bf, x_bf, flags, out);
}

// Round 9
// 240.695 us; speedup vs baseline: 1.9921x; 1.9921x over previous
//
#include <hip/hip_runtime.h>
#include <stdint.h>

#define EPS 1e-5f

typedef short bf16x8 __attribute__((ext_vector_type(8)));
typedef float f32x4 __attribute__((ext_vector_type(4)));

constexpr int M = 1024, N = 4096, K = 4096;
constexpr int BM = 64, BN = 128, BK = 64;
constexpr int NTK = K / BK;                       // 64 K-steps
constexpr int GRP = 8;                            // K-slabs per flag group
constexpr int NFLAGS = NTK / GRP;                 // 8
constexpr int KGRP = GRP * BK;                    // 512 cols per group
constexpr int PROD_BLOCKS = 256;
constexpr int CONS_BLOCKS = (M / BM) * (N / BN);  // 512
constexpr int GRID_TOTAL = PROD_BLOCKS + CONS_BLOCKS;
constexpr unsigned NPROD = PROD_BLOCKS;

// ---------- helpers ----------
__device__ __forceinline__ unsigned short f2bf(float f) {
  union { float f; uint32_t u; } v; v.f = f;
  uint32_t r = (v.u + 0x7fffu + ((v.u >> 16) & 1u)) >> 16;  // RNE
  return (unsigned short)r;
}

__device__ __forceinline__ void gload16(const void* g, void* l) {
  __builtin_amdgcn_global_load_lds(
      (const __attribute__((address_space(1))) void*)(uintptr_t)g,
      (__attribute__((address_space(3))) void*)(uintptr_t)l, 16, 0, 0);
}

__device__ __forceinline__ void cvt8(const f32x4& a0, const f32x4& a1,
                                     const f32x4& s0, const f32x4& s1,
                                     const f32x4& n0, const f32x4& n1,
                                     bf16x8& o) {
  o[0] = (short)f2bf(a0[0] + n0[0] * fmaxf(__expf(s0[0]), EPS));
  o[1] = (short)f2bf(a0[1] + n0[1] * fmaxf(__expf(s0[1]), EPS));
  o[2] = (short)f2bf(a0[2] + n0[2] * fmaxf(__expf(s0[2]), EPS));
  o[3] = (short)f2bf(a0[3] + n0[3] * fmaxf(__expf(s0[3]), EPS));
  o[4] = (short)f2bf(a1[0] + n1[0] * fmaxf(__expf(s1[0]), EPS));
  o[5] = (short)f2bf(a1[1] + n1[1] * fmaxf(__expf(s1[1]), EPS));
  o[6] = (short)f2bf(a1[2] + n1[2] * fmaxf(__expf(s1[2]), EPS));
  o[7] = (short)f2bf(a1[3] + n1[3] * fmaxf(__expf(s1[3]), EPS));
}

// wave-uniform relaxed spin on flags[g] (monotone counter -> no deadlock)
__device__ __forceinline__ void wait_flag(unsigned int* flags, int g) {
  const int lane = threadIdx.x & 63;
  unsigned v;
  do {
    unsigned tv = 0;
    if (lane == 0)
      tv = __hip_atomic_load(&flags[g], __ATOMIC_RELAXED, __HIP_MEMORY_SCOPE_AGENT);
    v = (unsigned)__shfl((int)tv, 0, 64);
    if (v < NPROD) __builtin_amdgcn_s_sleep(4);
  } while (v < NPROD);
}

// ---------- init: zero flags with agent-coherent atomics ----------
__global__ void init_flags_kernel(unsigned int* flags) {
  if (threadIdx.x < NFLAGS) atomicExch(&flags[threadIdx.x], 0u);
}

// ---------- fused overlap kernel ----------
// Blocks [0,256):   producers. Block p preps W rows [p*16,p*16+16), x rows [p*4,p*4+4)
//                   of each K-group in order, releasing flags[g] (+1, RELEASE) per group.
// Blocks [256,768): consumers. R4-proven GEMM (64x128 tile, 2-buf, __syncthreads loop),
//                   gated on flags[g] before staging each group's first slab.
__global__ __launch_bounds__(256, 2) void fused_kernel(
    const float* __restrict__ x,  const float* __restrict__ wm,
    const float* __restrict__ wsp, const float* __restrict__ bm,
    const float* __restrict__ bsp, const float* __restrict__ nb,
    const float* __restrict__ nw,
    unsigned short* __restrict__ w_bf, unsigned short* __restrict__ x_bf,
    unsigned int* __restrict__ flags, float* __restrict__ out)
{
  __shared__ unsigned short lds_mem[2][(BM + BN) * BK];  // 48 KB

  const int bid = blockIdx.x;
  const int tid = threadIdx.x;

  if (bid < PROD_BLOCKS) {
    // ================= producer =================
    const f32x4* wm4  = (const f32x4*)wm;
    const f32x4* wsp4 = (const f32x4*)wsp;
    const f32x4* nw4  = (const f32x4*)nw;
    const f32x4* x4   = (const f32x4*)x;
    bf16x8* wb8 = (bf16x8*)w_bf;
    bf16x8* xb8 = (bf16x8*)x_bf;

    const int wrow0 = bid * 16;
    const int xrow0 = bid * 4;

    for (int g = 0; g < NFLAGS; ++g) {
      const int colbase = g * KGRP;
      // W: 16 rows x 512 cols = 1024 bf16x8 stores = 4 iters; batch all 24 loads first
      f32x4 a[4][2], s[4][2], n[4][2];
      int wr[4], wc[4];
#pragma unroll
      for (int i = 0; i < 4; ++i) {
        const int idx = i * 256 + tid;                  // 0..1023
        wr[i] = wrow0 + (idx >> 6);                     // row const per wave
        wc[i] = colbase + (idx & 63) * 8;               // coalesced cols
        const int64_t i4 = ((int64_t)wr[i] * K + wc[i]) >> 2;
        a[i][0] = wm4[i4];      a[i][1] = wm4[i4 + 1];
        s[i][0] = wsp4[i4];     s[i][1] = wsp4[i4 + 1];
        n[i][0] = nw4[i4];      n[i][1] = nw4[i4 + 1];
      }
#pragma unroll
      for (int i = 0; i < 4; ++i) {
        bf16x8 o;
        cvt8(a[i][0], a[i][1], s[i][0], s[i][1], n[i][0], n[i][1], o);
        wb8[((int64_t)wr[i] * K + wc[i]) >> 3] = o;
      }
      // x: 4 rows x 512 cols = 256 stores = 1 iter
      {
        const int row = xrow0 + (tid >> 6);
        const int col = colbase + (tid & 63) * 8;
        const int64_t i4 = ((int64_t)row * K + col) >> 2;
        f32x4 v0 = x4[i4], v1 = x4[i4 + 1];
        bf16x8 o;
        o[0] = (short)f2bf(v0[0]); o[1] = (short)f2bf(v0[1]);
        o[2] = (short)f2bf(v0[2]); o[3] = (short)f2bf(v0[3]);
        o[4] = (short)f2bf(v1[0]); o[5] = (short)f2bf(v1[1]);
        o[6] = (short)f2bf(v1[2]); o[7] = (short)f2bf(v1[3]);
        xb8[((int64_t)row * K + col) >> 3] = o;
      }
      __syncthreads();   // drain this block's stores (per-wave vmcnt(0))
      if (tid == 0)
        __hip_atomic_fetch_add(&flags[g], 1u, __ATOMIC_RELEASE, __HIP_MEMORY_SCOPE_AGENT);
    }
    return;
  }

  // ================= consumer (R4 GEMM + group gates) =================
  const int lane = tid & 63;
  const int wid = tid >> 6;

  // entry acquire: per-wave cache invalidate (kills stale cross-replay L1/L2 lines)
  if (lane == 0)
    (void)__hip_atomic_load(&flags[0], __ATOMIC_ACQUIRE, __HIP_MEMORY_SCOPE_AGENT);

  const int cbid = bid - PROD_BLOCKS;
  const int lid = (cbid % 8) * (CONS_BLOCKS / 8) + cbid / 8;   // XCD swizzle, 512%8==0
  const int bc = lid >> 4;     // N-tile, 0..31
  const int br = lid & 15;     // M-tile, 0..15

  const int srow = wid * 8 + (lane >> 3);
  const int scol = ((lane & 7) ^ (lane >> 3)) * 8;   // pre-swizzled 16B slot
  const unsigned short* gA = x_bf + (int64_t)(br * BM + srow) * K + scol;
  const unsigned short* gB = w_bf + (int64_t)(bc * BN + srow) * K + scol;
  const int woff = wid * 8 * BK;

  auto stage = [&](int b, int t) {
    const unsigned short* ga = gA + t * BK;
    const unsigned short* gb = gB + t * BK;
    unsigned short* la = &lds_mem[b][0] + woff;
    unsigned short* lb = &lds_mem[b][BM * BK] + woff;
    gload16(ga,          la);
    gload16(ga + 32 * K, la + 32 * BK);
    gload16(gb,          lb);
    gload16(gb + 32 * K, lb + 32 * BK);
    gload16(gb + 64 * K, lb + 64 * BK);
    gload16(gb + 96 * K, lb + 96 * BK);
  };

  f32x4 acc[2][4] = {};
  const int fr = lane & 15;
  const int hi = lane >> 4;
  const int rl = lane & 7;
  const int c0 = ((hi ^ rl) << 3);
  const int c1 = (((4 + hi) ^ rl) << 3);
  const int am = (wid >> 1) * 32;
  const int an = (wid & 1) * 64;

  wait_flag(flags, 0);
  stage(0, 0);

  int cur = 0;
  for (int t = 0; t < NTK; ++t) {
    __syncthreads();                   // drains vmcnt/lgkmcnt; publishes buf[cur]
    if (t + 1 < NTK) {
      if (((t + 1) & (GRP - 1)) == 0) wait_flag(flags, (t + 1) >> 3);
      stage(cur ^ 1, t + 1);
    }
    const unsigned short* lA = &lds_mem[cur][0];
    const unsigned short* lB = &lds_mem[cur][BM * BK];
#pragma unroll
    for (int kk = 0; kk < 2; ++kk) {
      const int c = kk ? c1 : c0;
      bf16x8 a0 = *(const bf16x8*)&lA[(am +  0 + fr) * BK + c];
      bf16x8 a1 = *(const bf16x8*)&lA[(am + 16 + fr) * BK + c];
      bf16x8 b0 = *(const bf16x8*)&lB[(an +  0 + fr) * BK + c];
      bf16x8 b1 = *(const bf16x8*)&lB[(an + 16 + fr) * BK + c];
      bf16x8 b2 = *(const bf16x8*)&lB[(an + 32 + fr) * BK + c];
      bf16x8 b3 = *(const bf16x8*)&lB[(an + 48 + fr) * BK + c];
      acc[0][0] = __builtin_amdgcn_mfma_f32_16x16x32_bf16(a0, b0, acc[0][0], 0, 0, 0);
      acc[0][1] = __builtin_amdgcn_mfma_f32_16x16x32_bf16(a0, b1, acc[0][1], 0, 0, 0);
      acc[0][2] = __builtin_amdgcn_mfma_f32_16x16x32_bf16(a0, b2, acc[0][2], 0, 0, 0);
      acc[0][3] = __builtin_amdgcn_mfma_f32_16x16x32_bf16(a0, b3, acc[0][3], 0, 0, 0);
      acc[1][0] = __builtin_amdgcn_mfma_f32_16x16x32_bf16(a1, b0, acc[1][0], 0, 0, 0);
      acc[1][1] = __builtin_amdgcn_mfma_f32_16x16x32_bf16(a1, b1, acc[1][1], 0, 0, 0);
      acc[1][2] = __builtin_amdgcn_mfma_f32_16x16x32_bf16(a1, b2, acc[1][2], 0, 0, 0);
      acc[1][3] = __builtin_amdgcn_mfma_f32_16x16x32_bf16(a1, b3, acc[1][3], 0, 0, 0);
    }
    cur ^= 1;
  }

  // epilogue: inline bias; C/D layout col = lane&15, row = (lane>>4)*4 + reg
  const int orow0 = br * BM + am + hi * 4;
  const int ocol0 = bc * BN + an + fr;
#pragma unroll
  for (int j = 0; j < 4; ++j) {
    const int col = ocol0 + j * 16;
    const float bv = bm[col] + nb[col] * fmaxf(__expf(bsp[col]), EPS);
#pragma unroll
    for (int i = 0; i < 2; ++i) {
      const int row = orow0 + i * 16;
#pragma unroll
      for (int r = 0; r < 4; ++r)
        out[(int64_t)(row + r) * N + col] = acc[i][j][r] + bv;
    }
  }
}

// ---------- correctness fallback if workspace too small ----------
__global__ __launch_bounds__(256) void fallback_kernel(
    const float* __restrict__ x, const float* __restrict__ wm,
    const float* __restrict__ wsp, const float* __restrict__ bm,
    const float* __restrict__ bsp, const float* __restrict__ nw,
    const float* __restrict__ nb, float* __restrict__ out)
{
  int64_t idx = (int64_t)blockIdx.x * 256 + threadIdx.x;
  if (idx >= (int64_t)M * N) return;
  int b = (int)(idx >> 12);
  int o = (int)(idx & (N - 1));
  const float* xr = x + (int64_t)b * K;
  const float* wmr = wm + (int64_t)o * K;
  const float* wsr = wsp + (int64_t)o * K;
  const float* nwr = nw + (int64_t)o * K;
  float s = 0.f;
  for (int k = 0; k < K; ++k)
    s += xr[k] * (wmr[k] + nwr[k] * fmaxf(__expf(wsr[k]), EPS));
  out[idx] = s + bm[o] + nb[o] * fmaxf(__expf(bsp[o]), EPS);
}

extern "C" void kernel_launch(void* const* d_in, const int* in_sizes, int n_in,
                              void* d_out, int out_size, void* d_ws, size_t ws_size,
                              hipStream_t stream) {
  const float* x   = (const float*)d_in[0];
  const float* wm  = (const float*)d_in[1];
  const float* wsp = (const float*)d_in[2];
  const float* bm  = (const float*)d_in[3];
  const float* bsp = (const float*)d_in[4];
  const float* nw  = (const float*)d_in[5];
  const float* nb  = (const float*)d_in[6];
  float* out = (float*)d_out;

  const size_t w_bytes = (size_t)N * K * 2;
  const size_t x_bytes = (size_t)M * K * 2;
  const size_t f_bytes = 64 * sizeof(unsigned int);
  if (ws_size < w_bytes + x_bytes + f_bytes) {
    fallback_kernel<<<(int)(((int64_t)M * N + 255) / 256), 256, 0, stream>>>(
        x, wm, wsp, bm, bsp, nw, nb, out);
    return;
  }

  char* ws = (char*)d_ws;
  unsigned short* w_bf = (unsigned short*)ws;
  unsigned short* x_bf = (unsigned short*)(ws + w_bytes);
  unsigned int* flags = (unsigned int*)(ws + w_bytes + x_bytes);

  init_flags_kernel<<<1, 64, 0, stream>>>(flags);
  fused_kernel<<<GRID_TOTAL, 256, 0, stream>>>(x, wm, wsp, bm, bsp, nb, nw,
                                               w_bf, x_bf, flags, out);
}

// Round 10
// 90.650 us; speedup vs baseline: 5.2893x; 2.6552x over previous
//
#include <hip/hip_runtime.h>
#include <stdint.h>

#define EPS 1e-5f

typedef short bf16x8 __attribute__((ext_vector_type(8)));
typedef float f32x4 __attribute__((ext_vector_type(4)));

constexpr int M = 1024, N = 4096, K = 4096;
constexpr int BM = 64, BN = 128, BK = 64;
constexpr int KH = K / 2;                          // 2048 cols per half
constexpr int NTKH = KH / BK;                      // 32 K-steps per half
constexpr int CONS_BLOCKS = (M / BM) * (N / BN);   // 512 GEMM blocks
constexpr int PROD_BLOCKS = 256;                   // k1 producer blocks
constexpr int K0_BLOCKS = 1024;                    // k0 prep blocks
constexpr int64_t WPAIRS_H = (int64_t)N * KH / 8;  // 1,048,576 8-float pairs per W half
constexpr int64_t XPAIRS_H = (int64_t)M * KH / 8;  // 262,144 per x half

// ---------- helpers ----------
__device__ __forceinline__ unsigned short f2bf(float f) {
  union { float f; uint32_t u; } v; v.f = f;
  uint32_t r = (v.u + 0x7fffu + ((v.u >> 16) & 1u)) >> 16;  // RNE
  return (unsigned short)r;
}

__device__ __forceinline__ void gload16(const void* g, void* l) {
  __builtin_amdgcn_global_load_lds(
      (const __attribute__((address_space(1))) void*)(uintptr_t)g,
      (__attribute__((address_space(3))) void*)(uintptr_t)l, 16, 0, 0);
}

__device__ __forceinline__ void cvt8(const f32x4& a0, const f32x4& a1,
                                     const f32x4& s0, const f32x4& s1,
                                     const f32x4& n0, const f32x4& n1,
                                     bf16x8& o) {
  o[0] = (short)f2bf(a0[0] + n0[0] * fmaxf(__expf(s0[0]), EPS));
  o[1] = (short)f2bf(a0[1] + n0[1] * fmaxf(__expf(s0[1]), EPS));
  o[2] = (short)f2bf(a0[2] + n0[2] * fmaxf(__expf(s0[2]), EPS));
  o[3] = (short)f2bf(a0[3] + n0[3] * fmaxf(__expf(s0[3]), EPS));
  o[4] = (short)f2bf(a1[0] + n1[0] * fmaxf(__expf(s1[0]), EPS));
  o[5] = (short)f2bf(a1[1] + n1[1] * fmaxf(__expf(s1[1]), EPS));
  o[6] = (short)f2bf(a1[2] + n1[2] * fmaxf(__expf(s1[2]), EPS));
  o[7] = (short)f2bf(a1[3] + n1[3] * fmaxf(__expf(s1[3]), EPS));
}

// ---------- half-prep (device): convert K-cols [half*2048, half*2048+2048) ----------
// Pair layout: 256 pairs per row-half; p -> row = p>>8, pcol = p&255.
// Thread loads 2 consecutive float4 (32 B) per array -> prep-v4's 6.3 TB/s pattern.
__device__ __forceinline__ void prep_half(
    int half, int nb, int bi, int tid,
    const float* __restrict__ wm, const float* __restrict__ wsp,
    const float* __restrict__ nw, const float* __restrict__ x,
    unsigned short* __restrict__ w_bf, unsigned short* __restrict__ x_bf)
{
  const f32x4* wm4  = (const f32x4*)wm;
  const f32x4* wsp4 = (const f32x4*)wsp;
  const f32x4* nw4  = (const f32x4*)nw;
  const f32x4* x4   = (const f32x4*)x;
  bf16x8* wb8 = (bf16x8*)w_bf;
  bf16x8* xb8 = (bf16x8*)x_bf;
  const int hc4 = half * (KH / 4);   // float4 col offset
  const int hc8 = half * (KH / 8);   // bf16x8 col offset

  // ---- W half ----
  const int wpb = (int)(WPAIRS_H / nb);        // pairs per block
  const int wmac = wpb / 1024;                 // macro-iters of 4x256
  const int64_t wp0 = (int64_t)bi * wpb;
  for (int mi = 0; mi < wmac; ++mi) {
    f32x4 a[4][2], s[4][2], n[4][2];
    int64_t rr[4]; int pc[4];
#pragma unroll
    for (int j = 0; j < 4; ++j) {
      const int64_t p = wp0 + mi * 1024 + j * 256 + tid;
      rr[j] = p >> 8; pc[j] = (int)(p & 255);
      const int64_t i4 = rr[j] * (K / 4) + hc4 + pc[j] * 2;
      a[j][0] = wm4[i4];  a[j][1] = wm4[i4 + 1];
      s[j][0] = wsp4[i4]; s[j][1] = wsp4[i4 + 1];
      n[j][0] = nw4[i4];  n[j][1] = nw4[i4 + 1];
    }
#pragma unroll
    for (int j = 0; j < 4; ++j) {
      bf16x8 o;
      cvt8(a[j][0], a[j][1], s[j][0], s[j][1], n[j][0], n[j][1], o);
      wb8[rr[j] * (K / 8) + hc8 + pc[j]] = o;
    }
  }

  // ---- x half ----
  const int xpb = (int)(XPAIRS_H / nb);
  const int xit = xpb / 256;
  const int64_t xp0 = (int64_t)bi * xpb;
  for (int it = 0; it < xit; ++it) {
    const int64_t p = xp0 + it * 256 + tid;
    const int64_t row = p >> 8; const int pc = (int)(p & 255);
    const int64_t i4 = row * (K / 4) + hc4 + pc * 2;
    f32x4 v0 = x4[i4], v1 = x4[i4 + 1];
    bf16x8 o;
    o[0] = (short)f2bf(v0[0]); o[1] = (short)f2bf(v0[1]);
    o[2] = (short)f2bf(v0[2]); o[3] = (short)f2bf(v0[3]);
    o[4] = (short)f2bf(v1[0]); o[5] = (short)f2bf(v1[1]);
    o[6] = (short)f2bf(v1[2]); o[7] = (short)f2bf(v1[3]);
    xb8[row * (K / 8) + hc8 + pc] = o;
  }
}

// ---------- half-GEMM (device): R4-proven loop over K-cols [kbase, kbase+2048) ----------
// LDS swizzle both-sides: LDS(row, slot s) holds global slot s ^ (row&7) (16B slots).
__device__ __forceinline__ void gemm_half(
    int cbid, int kbase, bool accum, int tid,
    const unsigned short* __restrict__ Abf, const unsigned short* __restrict__ Bbf,
    const float* __restrict__ biasbuf, float* __restrict__ out,
    unsigned short* lds0)
{
  const int lane = tid & 63;
  const int wid = tid >> 6;

  const int lid = (cbid % 8) * (CONS_BLOCKS / 8) + cbid / 8;   // XCD swizzle, 512%8==0
  const int bc = lid >> 4;     // N-tile, 0..31
  const int br = lid & 15;     // M-tile, 0..15

  const int srow = wid * 8 + (lane >> 3);
  const int scol = ((lane & 7) ^ (lane >> 3)) * 8;
  const unsigned short* gA = Abf + (int64_t)(br * BM + srow) * K + kbase + scol;
  const unsigned short* gB = Bbf + (int64_t)(bc * BN + srow) * K + kbase + scol;
  const int woff = wid * 8 * BK;

  auto stage = [&](int b, int t) {
    const unsigned short* ga = gA + t * BK;
    const unsigned short* gb = gB + t * BK;
    unsigned short* la = lds0 + b * ((BM + BN) * BK) + woff;
    unsigned short* lb = la + BM * BK;
    gload16(ga,          la);
    gload16(ga + 32 * K, la + 32 * BK);
    gload16(gb,          lb);
    gload16(gb + 32 * K, lb + 32 * BK);
    gload16(gb + 64 * K, lb + 64 * BK);
    gload16(gb + 96 * K, lb + 96 * BK);
  };

  f32x4 acc[2][4] = {};
  const int fr = lane & 15;
  const int hi = lane >> 4;
  const int rl = lane & 7;
  const int c0 = ((hi ^ rl) << 3);
  const int c1 = (((4 + hi) ^ rl) << 3);
  const int am = (wid >> 1) * 32;
  const int an = (wid & 1) * 64;

  stage(0, 0);

  int cur = 0;
  for (int t = 0; t < NTKH; ++t) {
    __syncthreads();
    if (t + 1 < NTKH) stage(cur ^ 1, t + 1);
    const unsigned short* lA = lds0 + cur * ((BM + BN) * BK);
    const unsigned short* lB = lA + BM * BK;
#pragma unroll
    for (int kk = 0; kk < 2; ++kk) {
      const int c = kk ? c1 : c0;
      bf16x8 a0 = *(const bf16x8*)&lA[(am +  0 + fr) * BK + c];
      bf16x8 a1 = *(const bf16x8*)&lA[(am + 16 + fr) * BK + c];
      bf16x8 b0 = *(const bf16x8*)&lB[(an +  0 + fr) * BK + c];
      bf16x8 b1 = *(const bf16x8*)&lB[(an + 16 + fr) * BK + c];
      bf16x8 b2 = *(const bf16x8*)&lB[(an + 32 + fr) * BK + c];
      bf16x8 b3 = *(const bf16x8*)&lB[(an + 48 + fr) * BK + c];
      acc[0][0] = __builtin_amdgcn_mfma_f32_16x16x32_bf16(a0, b0, acc[0][0], 0, 0, 0);
      acc[0][1] = __builtin_amdgcn_mfma_f32_16x16x32_bf16(a0, b1, acc[0][1], 0, 0, 0);
      acc[0][2] = __builtin_amdgcn_mfma_f32_16x16x32_bf16(a0, b2, acc[0][2], 0, 0, 0);
      acc[0][3] = __builtin_amdgcn_mfma_f32_16x16x32_bf16(a0, b3, acc[0][3], 0, 0, 0);
      acc[1][0] = __builtin_amdgcn_mfma_f32_16x16x32_bf16(a1, b0, acc[1][0], 0, 0, 0);
      acc[1][1] = __builtin_amdgcn_mfma_f32_16x16x32_bf16(a1, b1, acc[1][1], 0, 0, 0);
      acc[1][2] = __builtin_amdgcn_mfma_f32_16x16x32_bf16(a1, b2, acc[1][2], 0, 0, 0);
      acc[1][3] = __builtin_amdgcn_mfma_f32_16x16x32_bf16(a1, b3, acc[1][3], 0, 0, 0);
    }
    cur ^= 1;
  }

  // epilogue: C/D layout col = lane&15, row = (lane>>4)*4 + reg
  const int orow0 = br * BM + am + hi * 4;
  const int ocol0 = bc * BN + an + fr;
#pragma unroll
  for (int j = 0; j < 4; ++j) {
    const int col = ocol0 + j * 16;
    const float bv = accum ? biasbuf[col] : 0.0f;
#pragma unroll
    for (int i = 0; i < 2; ++i) {
      const int row = orow0 + i * 16;
#pragma unroll
      for (int r = 0; r < 4; ++r) {
        const int64_t oi = (int64_t)(row + r) * N + col;
        float v = acc[i][j][r] + bv;
        if (accum) v += out[oi];
        out[oi] = v;
      }
    }
  }
}

// ---------- k0: prep half 0 + bias ----------
__global__ __launch_bounds__(256) void prep0_kernel(
    const float* __restrict__ wm, const float* __restrict__ wsp,
    const float* __restrict__ nw, const float* __restrict__ bm,
    const float* __restrict__ bsp, const float* __restrict__ nb_,
    const float* __restrict__ x,
    unsigned short* __restrict__ w_bf, unsigned short* __restrict__ x_bf,
    float* __restrict__ bias)
{
  prep_half(0, K0_BLOCKS, blockIdx.x, threadIdx.x, wm, wsp, nw, x, w_bf, x_bf);
  const int gt = blockIdx.x * 256 + threadIdx.x;
  if (gt < N / 4) {
    float4 a = ((const float4*)bm)[gt];
    float4 s = ((const float4*)bsp)[gt];
    float4 n = ((const float4*)nb_)[gt];
    float4 o;
    o.x = a.x + n.x * fmaxf(__expf(s.x), EPS);
    o.y = a.y + n.y * fmaxf(__expf(s.y), EPS);
    o.z = a.z + n.z * fmaxf(__expf(s.z), EPS);
    o.w = a.w + n.w * fmaxf(__expf(s.w), EPS);
    ((float4*)bias)[gt] = o;
  }
}

// ---------- k1: producers (prep half 1) + GEMM over half 0 (partial out) ----------
__global__ __launch_bounds__(256) void mid_kernel(
    const float* __restrict__ wm, const float* __restrict__ wsp,
    const float* __restrict__ nw, const float* __restrict__ x,
    unsigned short* __restrict__ w_bf, unsigned short* __restrict__ x_bf,
    const float* __restrict__ bias, float* __restrict__ out)
{
  __shared__ unsigned short lds_mem[2 * (BM + BN) * BK];  // 48 KB
  if (blockIdx.x < PROD_BLOCKS) {
    prep_half(1, PROD_BLOCKS, blockIdx.x, threadIdx.x, wm, wsp, nw, x, w_bf, x_bf);
    return;
  }
  gemm_half(blockIdx.x - PROD_BLOCKS, 0, false, threadIdx.x,
            x_bf, w_bf, bias, out, lds_mem);
}

// ---------- k2: GEMM over half 1, accumulate + bias ----------
__global__ __launch_bounds__(256) void last_kernel(
    const unsigned short* __restrict__ x_bf, const unsigned short* __restrict__ w_bf,
    const float* __restrict__ bias, float* __restrict__ out)
{
  __shared__ unsigned short lds_mem[2 * (BM + BN) * BK];  // 48 KB
  gemm_half(blockIdx.x, KH, true, threadIdx.x, x_bf, w_bf, bias, out, lds_mem);
}

// ---------- correctness fallback if workspace too small ----------
__global__ __launch_bounds__(256) void fallback_kernel(
    const float* __restrict__ x, const float* __restrict__ wm,
    const float* __restrict__ wsp, const float* __restrict__ bm,
    const float* __restrict__ bsp, const float* __restrict__ nw,
    const float* __restrict__ nb, float* __restrict__ out)
{
  int64_t idx = (int64_t)blockIdx.x * 256 + threadIdx.x;
  if (idx >= (int64_t)M * N) return;
  int b = (int)(idx >> 12);
  int o = (int)(idx & (N - 1));
  const float* xr = x + (int64_t)b * K;
  const float* wmr = wm + (int64_t)o * K;
  const float* wsr = wsp + (int64_t)o * K;
  const float* nwr = nw + (int64_t)o * K;
  float s = 0.f;
  for (int k = 0; k < K; ++k)
    s += xr[k] * (wmr[k] + nwr[k] * fmaxf(__expf(wsr[k]), EPS));
  out[idx] = s + bm[o] + nb[o] * fmaxf(__expf(bsp[o]), EPS);
}

extern "C" void kernel_launch(void* const* d_in, const int* in_sizes, int n_in,
                              void* d_out, int out_size, void* d_ws, size_t ws_size,
                              hipStream_t stream) {
  const float* x   = (const float*)d_in[0];
  const float* wm  = (const float*)d_in[1];
  const float* wsp = (const float*)d_in[2];
  const float* bm  = (const float*)d_in[3];
  const float* bsp = (const float*)d_in[4];
  const float* nw  = (const float*)d_in[5];
  const float* nb  = (const float*)d_in[6];
  float* out = (float*)d_out;

  const size_t w_bytes = (size_t)N * K * 2;
  const size_t x_bytes = (size_t)M * K * 2;
  const size_t b_bytes = (size_t)N * 4;
  if (ws_size < w_bytes + x_bytes + b_bytes) {
    fallback_kernel<<<(int)(((int64_t)M * N + 255) / 256), 256, 0, stream>>>(
        x, wm, wsp, bm, bsp, nw, nb, out);
    return;
  }

  char* ws = (char*)d_ws;
  unsigned short* w_bf = (unsigned short*)ws;
  unsigned short* x_bf = (unsigned short*)(ws + w_bytes);
  float* bias = (float*)(ws + w_bytes + x_bytes);

  prep0_kernel<<<K0_BLOCKS, 256, 0, stream>>>(wm, wsp, nw, bm, bsp, nb, x,
                                              w_bf, x_bf, bias);
  mid_kernel<<<PROD_BLOCKS + CONS_BLOCKS, 256, 0, stream>>>(wm, wsp, nw, x,
                                                            w_bf, x_bf, bias, out);
  last_kernel<<<CONS_BLOCKS, 256, 0, stream>>>(x_bf, w_bf, bias, out);
}